// Round 3
// baseline (1738.623 us; speedup 1.0000x reference)
//
#include <hip/hip_runtime.h>
#include <hip/hip_bf16.h>
#include <stdint.h>

#define S_LEN 4096
#define HID 2048
#define NH 16
#define KVH 8
#define DH 128
#define EPS 1e-6f
#define SCALE 0.08838834764831845f  // 128^-0.5

typedef __bf16 bf16x8 __attribute__((ext_vector_type(8)));
typedef __bf16 bf16x4 __attribute__((ext_vector_type(4)));
typedef float f32x4 __attribute__((ext_vector_type(4)));

// Async global->LDS, 16B per lane. LDS dest must be wave-uniform base;
// lane i lands at dst + i*16B (m97/m104-verified semantics).
__device__ inline void gl_lds16(const __bf16* g, __bf16* l) {
  __builtin_amdgcn_global_load_lds(
      (const __attribute__((address_space(1))) void*)g,
      (__attribute__((address_space(3))) void*)l, 16, 0, 0);
}

// ---------------------------------------------------------------------------
// fp32 -> bf16 bulk convert (4 elems/thread).
// ---------------------------------------------------------------------------
__global__ __launch_bounds__(256) void f2b4(
    const float* __restrict__ in, __bf16* __restrict__ out, int n4) {
  int i = blockIdx.x * 256 + threadIdx.x;
  if (i < n4) {
    float4 v = ((const float4*)in)[i];
    bf16x4 o;
    o[0] = (__bf16)v.x; o[1] = (__bf16)v.y; o[2] = (__bf16)v.z; o[3] = (__bf16)v.w;
    ((bf16x4*)out)[i] = o;
  }
}

// ---------------------------------------------------------------------------
// m97-structure NT GEMM: C(MxN) = A(MxK)@B(NxK)^T + bias. A,B bf16; C dtype TC.
// 128x128 block tile, BK=32, 4 waves (2x2), 16 MFMA/wave/K-step.
// bias_mode: 0 none, 1 per-col, 2 per-row.
// ---------------------------------------------------------------------------
template <typename TC>
__global__ __launch_bounds__(256) void gemm128(
    const __bf16* __restrict__ A, const __bf16* __restrict__ B,
    const float* __restrict__ bias, TC* __restrict__ C,
    int N, int K, int bias_mode)
{
  __shared__ __attribute__((aligned(16))) __bf16 As[128 * 32];
  __shared__ __attribute__((aligned(16))) __bf16 Bs[128 * 32];
  const int wave = threadIdx.x >> 6, lane = threadIdx.x & 63;
  const int quad = lane >> 4, l16 = lane & 15;
  const int wm = wave >> 1, wn = wave & 1;
  const int m0 = blockIdx.y * 128, n0 = blockIdx.x * 128;
  const int srow = lane >> 2, scol = (lane & 3) * 8;  // staging lane map

  f32x4 acc[4][4] = {};

  for (int k0 = 0; k0 < K; k0 += 32) {
    __syncthreads();  // previous iter's reads done before overwrite
#pragma unroll
    for (int j = wave; j < 8; j += 4) {   // j wave-uniform
      gl_lds16(A + (size_t)(m0 + j * 16 + srow) * K + k0 + scol, As + j * 512);
      gl_lds16(B + (size_t)(n0 + j * 16 + srow) * K + k0 + scol, Bs + j * 512);
    }
    __syncthreads();  // drains vmcnt before barrier (compiler-enforced)
    bf16x8 af[4], bfr[4];
#pragma unroll
    for (int s = 0; s < 4; ++s) {
      af[s]  = *(const bf16x8*)(As + (wm * 64 + s * 16 + l16) * 32 + quad * 8);
      bfr[s] = *(const bf16x8*)(Bs + (wn * 64 + s * 16 + l16) * 32 + quad * 8);
    }
#pragma unroll
    for (int ms = 0; ms < 4; ++ms)
#pragma unroll
      for (int ns = 0; ns < 4; ++ns)
        acc[ms][ns] = __builtin_amdgcn_mfma_f32_16x16x32_bf16(
            af[ms], bfr[ns], acc[ms][ns], 0, 0, 0);
  }

#pragma unroll
  for (int ms = 0; ms < 4; ++ms)
#pragma unroll
    for (int ns = 0; ns < 4; ++ns)
#pragma unroll
      for (int r = 0; r < 4; ++r) {
        int row = m0 + wm * 64 + ms * 16 + quad * 4 + r;
        int col = n0 + wn * 64 + ns * 16 + l16;
        float v = acc[ms][ns][r];
        if (bias_mode == 1) v += bias[col];
        else if (bias_mode == 2) v += bias[row];
        C[(size_t)row * N + col] = (TC)v;
      }
}

// ---------------------------------------------------------------------------
// Per-head RMSNorm (D=128) + RoPE, in-place on q,k (bf16). One wave/(s,head).
// SCALE (1/sqrt(D)) folded into q output so attn skips the per-score scale.
// ---------------------------------------------------------------------------
__global__ __launch_bounds__(256) void rmsnorm_rope(
    __bf16* __restrict__ q, __bf16* __restrict__ k,
    const float* __restrict__ cosb, const float* __restrict__ sinb,
    const float* __restrict__ qw, const float* __restrict__ kw)
{
  const int wave = threadIdx.x >> 6;
  const int lane = threadIdx.x & 63;
  const int row = blockIdx.x * 4 + wave;
  const int s   = row / (NH + KVH);
  const int idx = row % (NH + KVH);

  __bf16* base;
  const float* w;
  float oscale;
  if (idx < NH) { base = q + ((size_t)s * NH + idx) * DH;         w = qw; oscale = SCALE; }
  else          { base = k + ((size_t)s * KVH + (idx - NH)) * DH; w = kw; oscale = 1.0f; }

  float x1 = (float)base[lane];
  float x2 = (float)base[lane + 64];
  float ss = x1 * x1 + x2 * x2;
#pragma unroll
  for (int m = 1; m < 64; m <<= 1) ss += __shfl_xor(ss, m, 64);
  float inv = rsqrtf(ss * (1.0f / 128.0f) + EPS);

  float xh1 = x1 * inv * w[lane];
  float xh2 = x2 * inv * w[lane + 64];
  const float* cs = cosb + (size_t)s * DH;
  const float* sn = sinb + (size_t)s * DH;
  base[lane]      = (__bf16)((xh1 * cs[lane]      - xh2 * sn[lane])      * oscale);
  base[lane + 64] = (__bf16)((xh2 * cs[lane + 64] + xh1 * sn[lane + 64]) * oscale);
}

// ---------------------------------------------------------------------------
// Flash attention v4: causal, GQA reps=2. Grid (64, NH), block 128 (2 waves),
// one 64-row q-tile per block (qt = 63-bx: biggest blocks dispatch first).
// R2 post-mortem: swizzle killed conflicts (8.6e7->5.3e6) but time flat ->
// latency-bound at 1 wave/SIMD (grid-limited occupancy). This round:
//  - 1024 blocks x 2 waves = 8 waves/CU (2/SIMD): LDS 40KB (4 blocks/CU),
//    __launch_bounds__(128,2) caps VGPR at 256 (est ~240, no spill).
//  - V^T fragments in REGISTERS (T14 early-issue after QK^T, L2-resident),
//    no V LDS staging. K stays dbuf+swizzled via global_load_lds.
//  - causal mask only on diagonal tile (interior tiles provably unmasked);
//    SCALE pre-folded into q by rmsnorm_rope.
//  - T13 defer-max (THR=8): skip row-max shfl reduce + alpha rescale when
//    lane-local pmax - mrun <= 8 across the whole wave.
// P-slab: stride 64 elems, XOR-swizzled elem ^= (row&7)<<3 (write+read),
// 2-way max on both sides (free per m136).
// ---------------------------------------------------------------------------
__global__ __launch_bounds__(128, 2) void attn2(
    const __bf16* __restrict__ q,   // S x NH x DH  (pre-scaled by SCALE)
    const __bf16* __restrict__ k,   // S x KVH x DH
    const __bf16* __restrict__ vt,  // KVH x DH x S
    __bf16* __restrict__ o)         // S x NH x DH
{
  __shared__ __attribute__((aligned(16))) __bf16 Ks[2][64 * DH];   // 32KB swz
  __shared__ __attribute__((aligned(16))) __bf16 pl[2][32 * 64];   // 8KB swz
  const int wave = threadIdx.x >> 6, lane = threadIdx.x & 63;
  const int quad = lane >> 4, l16 = lane & 15;
  const int h = blockIdx.y, kvh = h >> 1;
  const int qt = 63 - (int)blockIdx.x;
  const int qbase = qt * 64 + wave * 32;

  const __bf16* kh = k + (size_t)kvh * DH;           // row s at + s*KVH*DH
  const __bf16* vh = vt + (size_t)kvh * DH * S_LEN;  // row d at + d*S_LEN

  // Stage one 64x128 K-tile into buffer `buf`. LDS dest linear; the
  // (row&7)<<4 byte-XOR is applied to the GLOBAL column (rule #21).
  auto stageK = [&](int buf, int k0) {
#pragma unroll
    for (int j = wave; j < 16; j += 2) {        // 4 K-rows per 1KB chunk
      int r  = j * 4 + (lane >> 4);
      int cb = ((lane & 15) * 16) ^ ((r & 7) << 4);
      gl_lds16(kh + (size_t)(k0 + r) * (KVH * DH) + (cb >> 1), &Ks[buf][j * 512]);
    }
  };

  // Q fragments: 2 row-subtiles x 4 d-chunks, register-resident
  bf16x8 qa[2][4];
#pragma unroll
  for (int rs = 0; rs < 2; ++rs) {
    const __bf16* qrow =
        q + ((size_t)(qbase + rs * 16 + l16) * NH + h) * DH + quad * 8;
#pragma unroll
    for (int c = 0; c < 4; ++c) qa[rs][c] = *(const bf16x8*)(qrow + c * 32);
  }

  f32x4 oacc[2][8] = {};
  float mrun[2][4], lrun[2][4];
#pragma unroll
  for (int rs = 0; rs < 2; ++rs)
#pragma unroll
    for (int r = 0; r < 4; ++r) { mrun[rs][r] = -3.0e38f; lrun[rs][r] = 0.0f; }

  stageK(0, 0);  // prologue: k-tile 0 -> buffer 0

  for (int kt = 0; kt <= qt; ++kt) {
    const int cur = kt & 1;
    const int k0 = kt * 64;
    __syncthreads();     // drains vmcnt: this tile's staged K landed
    if (kt < qt) stageK(cur ^ 1, k0 + 64);  // prefetch flies over compute

    const __bf16* ksb = Ks[cur];

    // ---- scores: each bk fragment feeds both row-subtiles ----
    f32x4 sc[2][4] = {};
#pragma unroll
    for (int tt = 0; tt < 4; ++tt) {
      const int row = tt * 16 + l16;
      const int swz = (row & 7) << 4;
#pragma unroll
      for (int c = 0; c < 4; ++c) {
        bf16x8 bk = *(const bf16x8*)(
            (const char*)ksb + row * 256 + ((c * 64 + quad * 16) ^ swz));
        sc[0][tt] = __builtin_amdgcn_mfma_f32_16x16x32_bf16(
            qa[0][c], bk, sc[0][tt], 0, 0, 0);
        sc[1][tt] = __builtin_amdgcn_mfma_f32_16x16x32_bf16(
            qa[1][c], bk, sc[1][tt], 0, 0, 0);
      }
    }

    // ---- V^T fragments -> registers (early issue; consumed in PV) ----
    bf16x8 vf[8][2];
#pragma unroll
    for (int c = 0; c < 8; ++c)
#pragma unroll
      for (int kc = 0; kc < 2; ++kc)
        vf[c][kc] = *(const bf16x8*)(
            vh + (size_t)(c * 16 + l16) * S_LEN + k0 + kc * 32 + quad * 8);

    // ---- causal mask: only the diagonal tile needs it ----
    if (kt == qt) {
#pragma unroll
      for (int rs = 0; rs < 2; ++rs)
#pragma unroll
        for (int tt = 0; tt < 4; ++tt)
#pragma unroll
          for (int r = 0; r < 4; ++r) {
            int col = k0 + tt * 16 + l16;
            int row = qbase + rs * 16 + quad * 4 + r;
            if (col > row) sc[rs][tt][r] = -3.0e38f;
          }
    }

    // ---- online softmax with T13 defer-max ----
    float pmax[2][4];
    bool defer = true;
#pragma unroll
    for (int rs = 0; rs < 2; ++rs)
#pragma unroll
      for (int r = 0; r < 4; ++r) {
        float mx = fmaxf(fmaxf(sc[rs][0][r], sc[rs][1][r]),
                         fmaxf(sc[rs][2][r], sc[rs][3][r]));
        pmax[rs][r] = mx;
        defer = defer && (mx - mrun[rs][r] <= 8.0f);
      }
    if (__all(defer)) {
      // keep old max: P bounded by e^8, bf16-safe; no oacc rescale
#pragma unroll
      for (int rs = 0; rs < 2; ++rs)
#pragma unroll
        for (int r = 0; r < 4; ++r) {
          float sum = 0.0f;
#pragma unroll
          for (int tt = 0; tt < 4; ++tt) {
            float p = __expf(sc[rs][tt][r] - mrun[rs][r]);
            sc[rs][tt][r] = p;
            sum += p;
          }
#pragma unroll
          for (int msk = 1; msk < 16; msk <<= 1)
            sum += __shfl_xor(sum, msk, 64);
          lrun[rs][r] += sum;
        }
    } else {
#pragma unroll
      for (int rs = 0; rs < 2; ++rs)
#pragma unroll
        for (int r = 0; r < 4; ++r) {
          float mx = pmax[rs][r];
#pragma unroll
          for (int msk = 1; msk < 16; msk <<= 1)
            mx = fmaxf(mx, __shfl_xor(mx, msk, 64));
          float mnew = fmaxf(mrun[rs][r], mx);
          float sum = 0.0f;
#pragma unroll
          for (int tt = 0; tt < 4; ++tt) {
            float p = __expf(sc[rs][tt][r] - mnew);
            sc[rs][tt][r] = p;
            sum += p;
          }
#pragma unroll
          for (int msk = 1; msk < 16; msk <<= 1)
            sum += __shfl_xor(sum, msk, 64);
          float alpha = __expf(mrun[rs][r] - mnew);
          lrun[rs][r] = lrun[rs][r] * alpha + sum;
          mrun[rs][r] = mnew;
#pragma unroll
          for (int c = 0; c < 8; ++c) oacc[rs][c][r] *= alpha;
        }
    }

    // ---- P: C-layout -> A-layout via per-wave swizzled slab ----
#pragma unroll
    for (int rs = 0; rs < 2; ++rs)
#pragma unroll
      for (int tt = 0; tt < 4; ++tt)
#pragma unroll
        for (int r = 0; r < 4; ++r) {
          int prow = rs * 16 + quad * 4 + r;
          pl[wave][prow * 64 + ((tt * 16 + l16) ^ ((prow & 7) << 3))] =
              (__bf16)sc[rs][tt][r];
        }
    bf16x8 pa[2][2];
#pragma unroll
    for (int rs = 0; rs < 2; ++rs)
#pragma unroll
      for (int kc = 0; kc < 2; ++kc) {
        int prow = rs * 16 + l16;
        pa[rs][kc] = *(const bf16x8*)(
            pl[wave] + prow * 64 + ((kc * 32 + quad * 8) ^ ((prow & 7) << 3)));
      }
    // ---- PV: V fragments from registers ----
#pragma unroll
    for (int c = 0; c < 8; ++c)
#pragma unroll
      for (int kc = 0; kc < 2; ++kc) {
        oacc[0][c] = __builtin_amdgcn_mfma_f32_16x16x32_bf16(
            pa[0][kc], vf[c][kc], oacc[0][c], 0, 0, 0);
        oacc[1][c] = __builtin_amdgcn_mfma_f32_16x16x32_bf16(
            pa[1][kc], vf[c][kc], oacc[1][c], 0, 0, 0);
      }
  }

  // ---- epilogue ----
#pragma unroll
  for (int rs = 0; rs < 2; ++rs)
#pragma unroll
    for (int c = 0; c < 8; ++c)
#pragma unroll
      for (int r = 0; r < 4; ++r) {
        int row = qbase + rs * 16 + quad * 4 + r;
        o[((size_t)row * NH + h) * DH + c * 16 + l16] =
            (__bf16)(oacc[rs][c][r] / lrun[rs][r]);
      }
}

// ---------------------------------------------------------------------------
extern "C" void kernel_launch(void* const* d_in, const int* in_sizes, int n_in,
                              void* d_out, int out_size, void* d_ws, size_t ws_size,
                              hipStream_t stream) {
  const float* x    = (const float*)d_in[0];
  const float* cosb = (const float*)d_in[1];
  const float* sinb = (const float*)d_in[2];
  // d_in[3] = mask (causal, reimplemented)
  const float* Wq  = (const float*)d_in[4];
  const float* bq  = (const float*)d_in[5];
  const float* Wk  = (const float*)d_in[6];
  const float* bk  = (const float*)d_in[7];
  const float* Wv  = (const float*)d_in[8];
  const float* bv  = (const float*)d_in[9];
  const float* Wo  = (const float*)d_in[10];
  const float* qnw = (const float*)d_in[11];
  const float* knw = (const float*)d_in[12];
  float* out = (float*)d_out;  // 4096x2048 fp32

  // ws (48 MB peak):
  char* ws = (char*)d_ws;
  __bf16* xb    = (__bf16*)(ws);                // 16 MB x bf16       (dies at memcpy)
  __bf16* Wqb   = (__bf16*)(ws + (16u << 20));  //  8 MB              (dies after q-GEMM)
  __bf16* Wkb   = (__bf16*)(ws + (24u << 20));  //  4 MB
  __bf16* Wvb   = (__bf16*)(ws + (28u << 20));  //  4 MB
  __bf16* kbuf  = (__bf16*)(ws + (32u << 20));  //  8 MB S x KVH x DH
  __bf16* vtbuf = (__bf16*)(ws + (40u << 20));  //  8 MB KVH x DH x S
  __bf16* Wob   = (__bf16*)(ws + (16u << 20));  //  8 MB (reuses Wqb slot)
  __bf16* aoc   = (__bf16*)(ws);                // 16 MB (reuses xb slot)
  // d_out doubles as scratch until the final GEMM:
  __bf16* qbuf = (__bf16*)d_out;                         // 16 MB S x NH x DH
  __bf16* ao   = (__bf16*)((char*)d_out + (16u << 20));  // 16 MB S x HID bf16

  dim3 blk(256);
  // fp32 -> bf16 converts
  f2b4<<<dim3(8192), blk, 0, stream>>>(x,  xb,  2097152);
  f2b4<<<dim3(4096), blk, 0, stream>>>(Wq, Wqb, 1048576);
  f2b4<<<dim3(2048), blk, 0, stream>>>(Wk, Wkb, 524288);
  f2b4<<<dim3(2048), blk, 0, stream>>>(Wv, Wvb, 524288);
  // q = x@Wq^T + bq  (4096x2048)
  gemm128<__bf16><<<dim3(16, 32), blk, 0, stream>>>(xb, Wqb, bq, qbuf, HID, HID, 1);
  // k = x@Wk^T + bk  (4096x1024)
  gemm128<__bf16><<<dim3(8, 32), blk, 0, stream>>>(xb, Wkb, bk, kbuf, KVH * DH, HID, 1);
  // v^T = Wv@x^T + bv[row]  (1024x4096)
  gemm128<__bf16><<<dim3(32, 8), blk, 0, stream>>>(Wvb, xb, bv, vtbuf, S_LEN, HID, 2);
  // rmsnorm + rope (in place; folds SCALE into q)
  rmsnorm_rope<<<dim3(S_LEN * (NH + KVH) / 4), blk, 0, stream>>>(
      qbuf, kbuf, cosb, sinb, qnw, knw);
  // attention -> ao (upper half of d_out)
  attn2<<<dim3(64, NH), dim3(128), 0, stream>>>(qbuf, kbuf, vtbuf, ao);
  // Wo convert (into dead Wqb slot) + move ao into dead xb slot
  f2b4<<<dim3(4096), blk, 0, stream>>>(Wo, Wob, 1048576);
  hipMemcpyAsync(aoc, ao, (size_t)S_LEN * HID * sizeof(__bf16),
                 hipMemcpyDeviceToDevice, stream);
  // out = ao @ Wo^T  (4096x2048, fp32 epilogue into full d_out)
  gemm128<float><<<dim3(16, 32), blk, 0, stream>>>(aoc, Wob, nullptr, out, HID, HID, 0);
}

// Round 4
// 573.478 us; speedup vs baseline: 3.0317x; 3.0317x over previous
//
#include <hip/hip_runtime.h>
#include <hip/hip_bf16.h>
#include <stdint.h>

#define S_LEN 4096
#define HID 2048
#define NH 16
#define KVH 8
#define DH 128
#define EPS 1e-6f
#define SCALE 0.08838834764831845f  // 128^-0.5

typedef __bf16 bf16x8 __attribute__((ext_vector_type(8)));
typedef __bf16 bf16x4 __attribute__((ext_vector_type(4)));
typedef float f32x4 __attribute__((ext_vector_type(4)));

// Async global->LDS, 16B per lane. LDS dest must be wave-uniform base;
// lane i lands at dst + i*16B (m97/m104-verified semantics).
__device__ inline void gl_lds16(const __bf16* g, __bf16* l) {
  __builtin_amdgcn_global_load_lds(
      (const __attribute__((address_space(1))) void*)g,
      (__attribute__((address_space(3))) void*)l, 16, 0, 0);
}

// ---------------------------------------------------------------------------
// fp32 -> bf16 bulk convert (4 elems/thread).
// ---------------------------------------------------------------------------
__global__ __launch_bounds__(256) void f2b4(
    const float* __restrict__ in, __bf16* __restrict__ out, int n4) {
  int i = blockIdx.x * 256 + threadIdx.x;
  if (i < n4) {
    float4 v = ((const float4*)in)[i];
    bf16x4 o;
    o[0] = (__bf16)v.x; o[1] = (__bf16)v.y; o[2] = (__bf16)v.z; o[3] = (__bf16)v.w;
    ((bf16x4*)out)[i] = o;
  }
}

// ---------------------------------------------------------------------------
// m97-structure NT GEMM: C(MxN) = A(MxK)@B(NxK)^T + bias. A,B bf16; C dtype TC.
// 128x128 block tile, BK=32, 4 waves (2x2), 16 MFMA/wave/K-step.
// bias_mode: 0 none, 1 per-col, 2 per-row.
// ---------------------------------------------------------------------------
template <typename TC>
__global__ __launch_bounds__(256) void gemm128(
    const __bf16* __restrict__ A, const __bf16* __restrict__ B,
    const float* __restrict__ bias, TC* __restrict__ C,
    int N, int K, int bias_mode)
{
  __shared__ __attribute__((aligned(16))) __bf16 As[128 * 32];
  __shared__ __attribute__((aligned(16))) __bf16 Bs[128 * 32];
  const int wave = threadIdx.x >> 6, lane = threadIdx.x & 63;
  const int quad = lane >> 4, l16 = lane & 15;
  const int wm = wave >> 1, wn = wave & 1;
  const int m0 = blockIdx.y * 128, n0 = blockIdx.x * 128;
  const int srow = lane >> 2, scol = (lane & 3) * 8;  // staging lane map

  f32x4 acc[4][4] = {};

  for (int k0 = 0; k0 < K; k0 += 32) {
    __syncthreads();  // previous iter's reads done before overwrite
#pragma unroll
    for (int j = wave; j < 8; j += 4) {   // j wave-uniform
      gl_lds16(A + (size_t)(m0 + j * 16 + srow) * K + k0 + scol, As + j * 512);
      gl_lds16(B + (size_t)(n0 + j * 16 + srow) * K + k0 + scol, Bs + j * 512);
    }
    __syncthreads();  // drains vmcnt before barrier (compiler-enforced)
    bf16x8 af[4], bfr[4];
#pragma unroll
    for (int s = 0; s < 4; ++s) {
      af[s]  = *(const bf16x8*)(As + (wm * 64 + s * 16 + l16) * 32 + quad * 8);
      bfr[s] = *(const bf16x8*)(Bs + (wn * 64 + s * 16 + l16) * 32 + quad * 8);
    }
#pragma unroll
    for (int ms = 0; ms < 4; ++ms)
#pragma unroll
      for (int ns = 0; ns < 4; ++ns)
        acc[ms][ns] = __builtin_amdgcn_mfma_f32_16x16x32_bf16(
            af[ms], bfr[ns], acc[ms][ns], 0, 0, 0);
  }

#pragma unroll
  for (int ms = 0; ms < 4; ++ms)
#pragma unroll
    for (int ns = 0; ns < 4; ++ns)
#pragma unroll
      for (int r = 0; r < 4; ++r) {
        int row = m0 + wm * 64 + ms * 16 + quad * 4 + r;
        int col = n0 + wn * 64 + ns * 16 + l16;
        float v = acc[ms][ns][r];
        if (bias_mode == 1) v += bias[col];
        else if (bias_mode == 2) v += bias[row];
        C[(size_t)row * N + col] = (TC)v;
      }
}

// ---------------------------------------------------------------------------
// Per-head RMSNorm (D=128) + RoPE, in-place on q,k (bf16). One wave/(s,head).
// SCALE (1/sqrt(D)) folded into q output so attn skips the per-score scale.
// ---------------------------------------------------------------------------
__global__ __launch_bounds__(256) void rmsnorm_rope(
    __bf16* __restrict__ q, __bf16* __restrict__ k,
    const float* __restrict__ cosb, const float* __restrict__ sinb,
    const float* __restrict__ qw, const float* __restrict__ kw)
{
  const int wave = threadIdx.x >> 6;
  const int lane = threadIdx.x & 63;
  const int row = blockIdx.x * 4 + wave;
  const int s   = row / (NH + KVH);
  const int idx = row % (NH + KVH);

  __bf16* base;
  const float* w;
  float oscale;
  if (idx < NH) { base = q + ((size_t)s * NH + idx) * DH;         w = qw; oscale = SCALE; }
  else          { base = k + ((size_t)s * KVH + (idx - NH)) * DH; w = kw; oscale = 1.0f; }

  float x1 = (float)base[lane];
  float x2 = (float)base[lane + 64];
  float ss = x1 * x1 + x2 * x2;
#pragma unroll
  for (int m = 1; m < 64; m <<= 1) ss += __shfl_xor(ss, m, 64);
  float inv = rsqrtf(ss * (1.0f / 128.0f) + EPS);

  float xh1 = x1 * inv * w[lane];
  float xh2 = x2 * inv * w[lane + 64];
  const float* cs = cosb + (size_t)s * DH;
  const float* sn = sinb + (size_t)s * DH;
  base[lane]      = (__bf16)((xh1 * cs[lane]      - xh2 * sn[lane])      * oscale);
  base[lane + 64] = (__bf16)((xh2 * cs[lane + 64] + xh1 * sn[lane + 64]) * oscale);
}

// ---------------------------------------------------------------------------
// Flash attention v5: R0's occupancy structure + R2's proven swizzle + R3's
// refcheck'd VALU diet. Causal, GQA reps=2. Grid (32, NH), block 256 (4
// waves), triangle pairing {bx, 63-bx} -> uniform 65 k-tiles/block.
// LDS 42KB -> 3 blocks/CU = 12 waves/CU (3/SIMD): at this occupancy the LDS
// pipe is the shared bottleneck, so the conflict fix (R0: 8.6e7 conflict
// cycles ~45% of kernel) converts to throughput (m252 regime-gate).
//  - Ks/Vs XOR-swizzled (byte ^= (row&7)<<4), both sides (rule #21):
//    pre-swizzled GLOBAL source for global_load_lds, same XOR on ds_read.
//  - causal mask only on diagonal tile; SCALE pre-folded into q.
//  - T13 defer-max (THR=8): skip row-max reduce + rescale on most tiles.
// R3 lessons applied: NO V-in-registers (spilled 1.4GB), NO launch_bounds
// minimum (allocator pressure -> spill).
// ---------------------------------------------------------------------------
__global__ __launch_bounds__(256) void attn2(
    const __bf16* __restrict__ q,   // S x NH x DH  (pre-scaled by SCALE)
    const __bf16* __restrict__ k,   // S x KVH x DH
    const __bf16* __restrict__ vt,  // KVH x DH x S
    __bf16* __restrict__ o)         // S x NH x DH
{
  __shared__ __attribute__((aligned(16))) __bf16 Ks[64 * DH];   // 16KB swz
  __shared__ __attribute__((aligned(16))) __bf16 Vs[DH * 64];   // 16KB swz
  __shared__ __attribute__((aligned(16))) __bf16 pl[4][16 * 72];// 9KB
  const int wave = threadIdx.x >> 6, lane = threadIdx.x & 63;
  const int quad = lane >> 4, l16 = lane & 15;
  const int h = blockIdx.y, kvh = h >> 1;

  const __bf16* kh = k + (size_t)kvh * DH;           // row s at + s*KVH*DH
  const __bf16* vh = vt + (size_t)kvh * DH * S_LEN;  // row d at + d*S_LEN

  for (int phase = 0; phase < 2; ++phase) {
    const int qt = phase == 0 ? (int)blockIdx.x : 63 - (int)blockIdx.x;
    const int qbase = qt * 64 + wave * 16;

    bf16x8 qa[4];
    const __bf16* qrow = q + ((size_t)(qbase + l16) * NH + h) * DH + quad * 8;
#pragma unroll
    for (int c = 0; c < 4; ++c) qa[c] = *(const bf16x8*)(qrow + c * 32);

    f32x4 oacc[8] = {};
    float mrun[4], lrun[4];
#pragma unroll
    for (int r = 0; r < 4; ++r) { mrun[r] = -3.0e38f; lrun[r] = 0.0f; }

    for (int kt = 0; kt <= qt; ++kt) {
      const int k0 = kt * 64;
      __syncthreads();  // all waves done with previous tile's LDS
      // stage K rows k0..k0+63 (global col pre-swizzled; LDS dest linear)
#pragma unroll
      for (int j = wave; j < 16; j += 4) {
        int r  = j * 4 + (lane >> 4);
        int cb = ((lane & 15) * 16) ^ ((r & 7) << 4);
        gl_lds16(kh + (size_t)(k0 + r) * (KVH * DH) + (cb >> 1), Ks + j * 512);
      }
      // stage V^T rows (d), cols k0..k0+63 (global col pre-swizzled)
#pragma unroll
      for (int j = wave; j < 16; j += 4) {
        int d  = j * 8 + (lane >> 3);
        int cb = ((lane & 7) * 16) ^ ((d & 7) << 4);
        gl_lds16(vh + (size_t)d * S_LEN + k0 + (cb >> 1), Vs + j * 512);
      }
      __syncthreads();  // drains global_load_lds (vmcnt) + barrier

      // ---- scores: 4 col-subtiles x 4 d-chunks (swizzled ds_read) ----
      f32x4 sc[4] = {};
#pragma unroll
      for (int tt = 0; tt < 4; ++tt) {
        const int row = tt * 16 + l16;
        const int swz = (row & 7) << 4;
#pragma unroll
        for (int c = 0; c < 4; ++c) {
          bf16x8 bk = *(const bf16x8*)(
              (const char*)Ks + row * 256 + ((c * 64 + quad * 16) ^ swz));
          sc[tt] = __builtin_amdgcn_mfma_f32_16x16x32_bf16(qa[c], bk, sc[tt], 0, 0, 0);
        }
      }
      // ---- causal mask: only the diagonal tile needs it (SCALE pre-folded) --
      if (kt == qt) {
#pragma unroll
        for (int tt = 0; tt < 4; ++tt)
#pragma unroll
          for (int r = 0; r < 4; ++r) {
            int col = k0 + tt * 16 + l16;
            int row = qbase + quad * 4 + r;
            if (col > row) sc[tt][r] = -3.0e38f;
          }
      }
      // ---- online softmax with T13 defer-max ----
      float pmax[4];
      bool defer = true;
#pragma unroll
      for (int r = 0; r < 4; ++r) {
        float mx = fmaxf(fmaxf(sc[0][r], sc[1][r]), fmaxf(sc[2][r], sc[3][r]));
        pmax[r] = mx;
        defer = defer && (mx - mrun[r] <= 8.0f);
      }
      if (__all(defer)) {
        // keep old max: P bounded by e^8, f32-safe; no oacc rescale
#pragma unroll
        for (int r = 0; r < 4; ++r) {
          float sum = 0.0f;
#pragma unroll
          for (int tt = 0; tt < 4; ++tt) {
            float p = __expf(sc[tt][r] - mrun[r]);
            sc[tt][r] = p;
            sum += p;
          }
#pragma unroll
          for (int msk = 1; msk < 16; msk <<= 1) sum += __shfl_xor(sum, msk, 64);
          lrun[r] += sum;
        }
      } else {
#pragma unroll
        for (int r = 0; r < 4; ++r) {
          float mx = pmax[r];
#pragma unroll
          for (int msk = 1; msk < 16; msk <<= 1) mx = fmaxf(mx, __shfl_xor(mx, msk, 64));
          float mnew = fmaxf(mrun[r], mx);
          float sum = 0.0f;
#pragma unroll
          for (int tt = 0; tt < 4; ++tt) {
            float p = __expf(sc[tt][r] - mnew);
            sc[tt][r] = p;
            sum += p;
          }
#pragma unroll
          for (int msk = 1; msk < 16; msk <<= 1) sum += __shfl_xor(sum, msk, 64);
          float alpha = __expf(mrun[r] - mnew);
          lrun[r] = lrun[r] * alpha + sum;
          mrun[r] = mnew;
#pragma unroll
          for (int c = 0; c < 8; ++c) oacc[c][r] *= alpha;
        }
      }
      // ---- P: C-layout -> A-layout via per-wave slab (stride 72) ----
#pragma unroll
      for (int tt = 0; tt < 4; ++tt)
#pragma unroll
        for (int r = 0; r < 4; ++r)
          pl[wave][(quad * 4 + r) * 72 + tt * 16 + l16] = (__bf16)sc[tt][r];
      bf16x8 pa[2];
#pragma unroll
      for (int kc = 0; kc < 2; ++kc)
        pa[kc] = *(const bf16x8*)(pl[wave] + l16 * 72 + kc * 32 + quad * 8);
      // ---- PV: 8 d-chunks x 2 k-chunks (swizzled ds_read) ----
#pragma unroll
      for (int c = 0; c < 8; ++c)
#pragma unroll
        for (int kc = 0; kc < 2; ++kc) {
          const int d = c * 16 + l16;
          bf16x8 bv = *(const bf16x8*)(
              (const char*)Vs + d * 128 + ((kc * 64 + quad * 16) ^ ((d & 7) << 4)));
          oacc[c] = __builtin_amdgcn_mfma_f32_16x16x32_bf16(pa[kc], bv, oacc[c], 0, 0, 0);
        }
    }

    // ---- epilogue ----
#pragma unroll
    for (int c = 0; c < 8; ++c)
#pragma unroll
      for (int r = 0; r < 4; ++r) {
        int row = qbase + quad * 4 + r;
        o[((size_t)row * NH + h) * DH + c * 16 + l16] = (__bf16)(oacc[c][r] / lrun[r]);
      }
  }
}

// ---------------------------------------------------------------------------
extern "C" void kernel_launch(void* const* d_in, const int* in_sizes, int n_in,
                              void* d_out, int out_size, void* d_ws, size_t ws_size,
                              hipStream_t stream) {
  const float* x    = (const float*)d_in[0];
  const float* cosb = (const float*)d_in[1];
  const float* sinb = (const float*)d_in[2];
  // d_in[3] = mask (causal, reimplemented)
  const float* Wq  = (const float*)d_in[4];
  const float* bq  = (const float*)d_in[5];
  const float* Wk  = (const float*)d_in[6];
  const float* bk  = (const float*)d_in[7];
  const float* Wv  = (const float*)d_in[8];
  const float* bv  = (const float*)d_in[9];
  const float* Wo  = (const float*)d_in[10];
  const float* qnw = (const float*)d_in[11];
  const float* knw = (const float*)d_in[12];
  float* out = (float*)d_out;  // 4096x2048 fp32

  // ws (48 MB peak):
  char* ws = (char*)d_ws;
  __bf16* xb    = (__bf16*)(ws);                // 16 MB x bf16       (dies at memcpy)
  __bf16* Wqb   = (__bf16*)(ws + (16u << 20));  //  8 MB              (dies after q-GEMM)
  __bf16* Wkb   = (__bf16*)(ws + (24u << 20));  //  4 MB
  __bf16* Wvb   = (__bf16*)(ws + (28u << 20));  //  4 MB
  __bf16* kbuf  = (__bf16*)(ws + (32u << 20));  //  8 MB S x KVH x DH
  __bf16* vtbuf = (__bf16*)(ws + (40u << 20));  //  8 MB KVH x DH x S
  __bf16* Wob   = (__bf16*)(ws + (16u << 20));  //  8 MB (reuses Wqb slot)
  __bf16* aoc   = (__bf16*)(ws);                // 16 MB (reuses xb slot)
  // d_out doubles as scratch until the final GEMM:
  __bf16* qbuf = (__bf16*)d_out;                         // 16 MB S x NH x DH
  __bf16* ao   = (__bf16*)((char*)d_out + (16u << 20));  // 16 MB S x HID bf16

  dim3 blk(256);
  // fp32 -> bf16 converts
  f2b4<<<dim3(8192), blk, 0, stream>>>(x,  xb,  2097152);
  f2b4<<<dim3(4096), blk, 0, stream>>>(Wq, Wqb, 1048576);
  f2b4<<<dim3(2048), blk, 0, stream>>>(Wk, Wkb, 524288);
  f2b4<<<dim3(2048), blk, 0, stream>>>(Wv, Wvb, 524288);
  // q = x@Wq^T + bq  (4096x2048)
  gemm128<__bf16><<<dim3(16, 32), blk, 0, stream>>>(xb, Wqb, bq, qbuf, HID, HID, 1);
  // k = x@Wk^T + bk  (4096x1024)
  gemm128<__bf16><<<dim3(8, 32), blk, 0, stream>>>(xb, Wkb, bk, kbuf, KVH * DH, HID, 1);
  // v^T = Wv@x^T + bv[row]  (1024x4096)
  gemm128<__bf16><<<dim3(32, 8), blk, 0, stream>>>(Wvb, xb, bv, vtbuf, S_LEN, HID, 2);
  // rmsnorm + rope (in place; folds SCALE into q)
  rmsnorm_rope<<<dim3(S_LEN * (NH + KVH) / 4), blk, 0, stream>>>(
      qbuf, kbuf, cosb, sinb, qnw, knw);
  // attention -> ao (upper half of d_out)
  attn2<<<dim3(32, NH), blk, 0, stream>>>(qbuf, kbuf, vtbuf, ao);
  // Wo convert (into dead Wqb slot) + move ao into dead xb slot
  f2b4<<<dim3(4096), blk, 0, stream>>>(Wo, Wob, 1048576);
  hipMemcpyAsync(aoc, ao, (size_t)S_LEN * HID * sizeof(__bf16),
                 hipMemcpyDeviceToDevice, stream);
  // out = ao @ Wo^T  (4096x2048, fp32 epilogue into full d_out)
  gemm128<float><<<dim3(16, 32), blk, 0, stream>>>(aoc, Wob, nullptr, out, HID, HID, 0);
}